// Round 2
// baseline (647.448 us; speedup 1.0000x reference)
//
#include <hip/hip_runtime.h>

typedef __attribute__((ext_vector_type(8))) short bf16x8;
typedef __attribute__((ext_vector_type(4))) float f32x4;

__device__ inline float bf2f(unsigned short u) {
    union { float f; unsigned int i; } v; v.i = ((unsigned int)u) << 16; return v.f;
}
__device__ inline unsigned short f2bf(float f) {
    union { float f; unsigned int u; } v; v.f = f;
    unsigned int x = v.u;
    unsigned int r = x + 0x7FFFu + ((x >> 16) & 1u);
    return (unsigned short)(r >> 16);
}
// order-preserving float <-> uint for atomicMax
__device__ inline unsigned int fenc(float x) {
    union { float f; unsigned int u; } v; v.f = x;
    return (v.u & 0x80000000u) ? ~v.u : (v.u | 0x80000000u);
}
__device__ inline float fdec(unsigned int k) {
    union { float f; unsigned int u; } v;
    v.u = (k & 0x80000000u) ? (k & 0x7FFFFFFFu) : ~k;
    return v.f;
}
// dual-format loads: f32flag ? float32 buffer : bf16 buffer
__device__ inline float ldf(const void* p, size_t i, int f32) {
    return f32 ? ((const float*)p)[i] : bf2f(((const unsigned short*)p)[i]);
}
// i64flag ? int64 buffer (values < 2^31, take low word) : int32 buffer
__device__ inline int ldi(const int* p, size_t i, int i64) {
    return i64 ? p[2 * i] : p[i];
}

// ---------------- format detection (device-side, deterministic) ----------------
__global__ __launch_bounds__(256)
void k_detect(const unsigned short* __restrict__ xu, int xstride,
              const int* __restrict__ ei, int estride, int* __restrict__ flags) {
    __shared__ int cnt, orv;
    if (threadIdx.x == 0) { cnt = 0; orv = 0; }
    __syncthreads();
    int c = 0, o = 0;
    for (int s = 0; s < 4; ++s) {
        int j = threadIdx.x * 4 + s;               // 0..1023
        size_t k = (size_t)j * xstride;            // < xelems/2
        unsigned short u = xu[2 * k];              // even ushort
        int e = (u >> 7) & 0xFF;
        if (e >= 100 && e <= 140) ++c;             // sane bf16 exponent?
        size_t idx = (size_t)j * estride;          // < E
        o |= ei[2 * idx + 1];                      // odd word
    }
    atomicAdd(&cnt, c); atomicOr(&orv, o);
    __syncthreads();
    if (threadIdx.x == 0) {
        flags[0] = (cnt < 768) ? 1 : 0;   // 1 => floats are f32
        flags[1] = (orv == 0) ? 1 : 0;    // 1 => ints are int64
    }
}

// ---------------- CSR build ----------------
__global__ void k_hist(const int* __restrict__ ei, int E, int N,
                       int* __restrict__ hist, const int* __restrict__ flags) {
    int e = blockIdx.x * 256 + threadIdx.x;
    if (e >= E) return;
    int i64 = flags[1];
    int d = ldi(ei, (size_t)E + e, i64); d = d < 0 ? 0 : (d >= N ? N - 1 : d);
    atomicAdd(&hist[d], 1);
}

__global__ void k_dinv(const int* __restrict__ hist, float* __restrict__ dinv, int N) {
    int i = blockIdx.x * 256 + threadIdx.x;
    if (i < N) dinv[i] = rsqrtf((float)(hist[i] + 1));
}

__global__ __launch_bounds__(1024)
void k_scan(const int* __restrict__ hist, int* __restrict__ rowptr, int N) {
    __shared__ int ssum[1024];
    int t = threadIdx.x;
    int chunk = (N + 1023) / 1024;
    int lo = t * chunk, hi = lo + chunk; if (hi > N) hi = N; if (lo > N) lo = N;
    int s = 0;
    for (int i = lo; i < hi; ++i) s += hist[i];
    ssum[t] = s;
    __syncthreads();
    for (int off = 1; off < 1024; off <<= 1) {
        int v = (t >= off) ? ssum[t - off] : 0;
        __syncthreads();
        ssum[t] += v;
        __syncthreads();
    }
    int run = ssum[t] - s;
    for (int i = lo; i < hi; ++i) { rowptr[i] = run; run += hist[i]; }
    if (t == 1023) rowptr[N] = ssum[1023];
}

__global__ void k_scatter(const int* __restrict__ ei, int E, int N,
                          const int* __restrict__ rowptr, int* __restrict__ cursor,
                          int* __restrict__ col, const int* __restrict__ flags) {
    int e = blockIdx.x * 256 + threadIdx.x;
    if (e >= E) return;
    int i64 = flags[1];
    int s = ldi(ei, (size_t)e, i64);     s = s < 0 ? 0 : (s >= N ? N - 1 : s);
    int d = ldi(ei, (size_t)E + e, i64); d = d < 0 ? 0 : (d >= N ? N - 1 : d);
    int pos = rowptr[d] + atomicAdd(&cursor[d], 1);
    col[pos] = s;
}

// ---------------- weight folding (fp32 math, bf16 store) ----------------
// Wt0[n*256+k] = 2*(pw(0,0)@gw(0,0))[k][n] + (pw(0,1)@gw(0,1))[k][n]
// Wt1[n*512+k]     = 2*(pw(1,0)@gw(1,0))[k][n]
// Wt1[n*512+256+k] =   (pw(1,1)@gw(1,1))[k][n]
__global__ void k_prepw(const void* __restrict__ pre_w, const void* __restrict__ gcn_w,
                        unsigned short* __restrict__ Wt0, unsigned short* __restrict__ Wt1,
                        const int* __restrict__ flags) {
    int k = blockIdx.x, which = blockIdx.y, n = threadIdx.x;
    int f = flags[0];
    if (which == 0) {
        size_t p0 = ((size_t)(0 * 2 + 0) * 256 + k) * 256;
        size_t g0 = (size_t)(0 * 2 + 0) * 256 * 256;
        size_t p1 = ((size_t)(0 * 2 + 1) * 256 + k) * 256;
        size_t g1 = (size_t)(0 * 2 + 1) * 256 * 256;
        float a = 0.f, b = 0.f;
        for (int m = 0; m < 256; ++m) {
            a += ldf(pre_w, p0 + m, f) * ldf(gcn_w, g0 + m * 256 + n, f);
            b += ldf(pre_w, p1 + m, f) * ldf(gcn_w, g1 + m * 256 + n, f);
        }
        Wt0[n * 256 + k] = f2bf(2.f * a + b);
    } else if (which == 1) {
        size_t p = ((size_t)(1 * 2 + 0) * 256 + k) * 256;
        size_t g = (size_t)(1 * 2 + 0) * 256 * 256;
        float a = 0.f;
        for (int m = 0; m < 256; ++m) a += ldf(pre_w, p + m, f) * ldf(gcn_w, g + m * 256 + n, f);
        Wt1[n * 512 + k] = f2bf(2.f * a);
    } else {
        size_t p = ((size_t)(1 * 2 + 1) * 256 + k) * 256;
        size_t g = (size_t)(1 * 2 + 1) * 256 * 256;
        float a = 0.f;
        for (int m = 0; m < 256; ++m) a += ldf(pre_w, p + m, f) * ldf(gcn_w, g + m * 256 + n, f);
        Wt1[n * 512 + 256 + k] = f2bf(a);
    }
}

__global__ void k_prepb(const void* __restrict__ pre_b, const void* __restrict__ gcn_w,
                        const void* __restrict__ gcn_b,
                        float* __restrict__ cvec, float* __restrict__ dvec,
                        const int* __restrict__ flags) {
    int l = blockIdx.x, n = threadIdx.x;
    int f = flags[0];
    size_t pb0 = (size_t)(l * 2 + 0) * 256;
    size_t pb1 = (size_t)(l * 2 + 1) * 256;
    size_t g0 = (size_t)(l * 2 + 0) * 256 * 256;
    size_t g1 = (size_t)(l * 2 + 1) * 256 * 256;
    float a = 0.f, b = 0.f;
    for (int m = 0; m < 256; ++m) {
        a += ldf(pre_b, pb0 + m, f) * ldf(gcn_w, g0 + m * 256 + n, f);
        b += ldf(pre_b, pb1 + m, f) * ldf(gcn_w, g1 + m * 256 + n, f);
    }
    cvec[l * 256 + n] = 2.f * a + b;
    dvec[l * 256 + n] = 2.f * ldf(gcn_b, (size_t)(l * 2 + 0) * 256 + n, f)
                            + ldf(gcn_b, (size_t)(l * 2 + 1) * 256 + n, f);
}

// ---------------- main GEMM: out[i,:] = dinv[i] * (A[i,:] @ W + c) ----------------
// A row: k<256 from Xraw (f32 or bf16 per flag), k>=256 from Yb (always bf16)
// Wt is [256 x K] bf16 (W transposed). 128x128 tile, BK=64, 4 waves, XOR-swizzled LDS.
__global__ __launch_bounds__(256)
void k_gemm(const void* __restrict__ Xraw, const unsigned short* __restrict__ Yb,
            const unsigned short* __restrict__ Wt, const float* __restrict__ cvec,
            const float* __restrict__ dinv, unsigned short* __restrict__ out,
            int M, int K, const int* __restrict__ flags) {
    __shared__ unsigned short lds[2 * 128 * 64];  // A tile + W tile, 16KB each
    char* ldsb = (char*)lds;
    const int tid = threadIdx.x;
    const int lane = tid & 63;
    const int wid = tid >> 6;
    const int wm = wid >> 1, wn = wid & 1;
    const int row0 = blockIdx.x * 128;
    const int bn = blockIdx.y;
    const int xf32 = flags[0];

    f32x4 acc[4][4] = {};
    const int KT = K / 64;
    for (int kt = 0; kt < KT; ++kt) {
        const int k0 = kt * 64;
        const int ak0 = (k0 < 256) ? k0 : k0 - 256;
        int4 ra[4], rw[4];
#pragma unroll
        for (int q = 0; q < 4; ++q) {
            int id = q * 256 + tid;        // 0..1023 chunks of 16B (8 bf16)
            int r = id >> 3;               // tile row 0..127
            int cb = id & 7;               // chunk in row
            int grow = row0 + r; if (grow > M - 1) grow = M - 1;
            size_t eoff = (size_t)grow * 256 + ak0 + cb * 8;
            if (k0 < 256) {
                if (xf32) {
                    const float* s = (const float*)Xraw + eoff;
                    float4 f0 = *(const float4*)s;
                    float4 f1 = *(const float4*)(s + 4);
                    ra[q].x = (int)f2bf(f0.x) | ((int)f2bf(f0.y) << 16);
                    ra[q].y = (int)f2bf(f0.z) | ((int)f2bf(f0.w) << 16);
                    ra[q].z = (int)f2bf(f1.x) | ((int)f2bf(f1.y) << 16);
                    ra[q].w = (int)f2bf(f1.z) | ((int)f2bf(f1.w) << 16);
                } else {
                    ra[q] = *(const int4*)((const unsigned short*)Xraw + eoff);
                }
            } else {
                ra[q] = *(const int4*)(Yb + eoff);
            }
            rw[q] = *(const int4*)(Wt + (size_t)(bn * 128 + r) * K + k0 + cb * 8);
        }
        __syncthreads();   // prior LDS reads done
#pragma unroll
        for (int q = 0; q < 4; ++q) {
            int id = q * 256 + tid;
            int r = id >> 3, cb = id & 7;
            int sw = (cb * 16) ^ ((r & 7) << 4);
            *(int4*)(ldsb + r * 128 + sw) = ra[q];
            *(int4*)(ldsb + 16384 + r * 128 + sw) = rw[q];
        }
        __syncthreads();
#pragma unroll
        for (int kk = 0; kk < 2; ++kk) {
            bf16x8 af[4], bfr[4];
            int byte = kk * 64 + ((lane >> 4) << 4);
#pragma unroll
            for (int m = 0; m < 4; ++m) {
                int r = wm * 64 + m * 16 + (lane & 15);
                af[m] = *(const bf16x8*)(ldsb + r * 128 + (byte ^ ((r & 7) << 4)));
            }
#pragma unroll
            for (int n = 0; n < 4; ++n) {
                int r = wn * 64 + n * 16 + (lane & 15);
                bfr[n] = *(const bf16x8*)(ldsb + 16384 + r * 128 + (byte ^ ((r & 7) << 4)));
            }
#pragma unroll
            for (int m = 0; m < 4; ++m)
#pragma unroll
                for (int n = 0; n < 4; ++n)
                    acc[m][n] = __builtin_amdgcn_mfma_f32_16x16x32_bf16(af[m], bfr[n], acc[m][n], 0, 0, 0);
        }
    }
    // epilogue: val = (acc + c[col]) * dinv[row], bf16 store
#pragma unroll
    for (int m = 0; m < 4; ++m) {
#pragma unroll
        for (int j = 0; j < 4; ++j) {
            int rt = wm * 64 + m * 16 + ((lane >> 4) << 2) + j;
            int grow = row0 + rt;
            if (grow < M) {
                float di = dinv[grow];
#pragma unroll
                for (int n = 0; n < 4; ++n) {
                    int colc = bn * 128 + wn * 64 + n * 16 + (lane & 15);
                    float v = (acc[m][n][j] + cvec[colc]) * di;
                    out[(size_t)grow * 256 + colc] = f2bf(v);
                }
            }
        }
    }
}

// ---------------- aggregation: Y[i] = dinv[i]*(U[i] + sum_{j in in(i)} U[j]) + d ----------------
__global__ __launch_bounds__(256)
void k_agg(const unsigned short* __restrict__ U, const int* __restrict__ rowptr,
           const int* __restrict__ col, const float* __restrict__ dinv,
           const float* __restrict__ dvec, unsigned short* __restrict__ Y, int N) {
    int w = (blockIdx.x * 256 + threadIdx.x) >> 6;   // node per wave
    int lane = threadIdx.x & 63;
    if (w >= N) return;
    ushort4 sv = *(const ushort4*)(U + (size_t)w * 256 + lane * 4);
    float a0 = bf2f(sv.x), a1 = bf2f(sv.y), a2 = bf2f(sv.z), a3 = bf2f(sv.w);
    int beg = rowptr[w], end = rowptr[w + 1];
    for (int e = beg; e < end; ++e) {
        int s = col[e];
        ushort4 v = *(const ushort4*)(U + (size_t)s * 256 + lane * 4);
        a0 += bf2f(v.x); a1 += bf2f(v.y); a2 += bf2f(v.z); a3 += bf2f(v.w);
    }
    float di = dinv[w];
    int f = lane * 4;
    a0 = a0 * di + dvec[f + 0];
    a1 = a1 * di + dvec[f + 1];
    a2 = a2 * di + dvec[f + 2];
    a3 = a3 * di + dvec[f + 3];
    ushort4 o; o.x = f2bf(a0); o.y = f2bf(a1); o.z = f2bf(a2); o.w = f2bf(a3);
    *(ushort4*)(Y + (size_t)w * 256 + lane * 4) = o;
}

// ---------------- pooling (batch is sorted) ----------------
__global__ __launch_bounds__(256)
void k_pool(const unsigned short* __restrict__ Y, const int* __restrict__ batch, int N,
            float* __restrict__ psum, unsigned int* __restrict__ pkey, int* __restrict__ pcnt,
            const int* __restrict__ flags) {
    int f = threadIdx.x;
    int base = blockIdx.x * 64;
    if (base >= N) return;
    int i64 = flags[1];
    int g0 = ldi(batch, base, i64); int curg = g0 < 0 ? 0 : (g0 > 63 ? 63 : g0);
    float s = 0.f, mx = -__builtin_inff(); int cnt = 0;
    for (int r = 0; r < 64; ++r) {
        int node = base + r;
        if (node >= N) break;
        int g = ldi(batch, node, i64); g = g < 0 ? 0 : (g > 63 ? 63 : g);
        if (g != curg) {
            atomicAdd(&psum[curg * 256 + f], s);
            atomicMax(&pkey[curg * 256 + f], fenc(mx));
            if (f == 0) atomicAdd(&pcnt[curg], cnt);
            curg = g; s = 0.f; mx = -__builtin_inff(); cnt = 0;
        }
        float v = bf2f(Y[(size_t)node * 256 + f]);
        s += v; mx = fmaxf(mx, v); ++cnt;
    }
    atomicAdd(&psum[curg * 256 + f], s);
    atomicMax(&pkey[curg * 256 + f], fenc(mx));
    if (f == 0) atomicAdd(&pcnt[curg], cnt);
}

// ---------------- classifier ----------------
__global__ __launch_bounds__(64)
void k_cls(const float* __restrict__ psum, const unsigned int* __restrict__ pkey,
           const int* __restrict__ pcnt, const void* __restrict__ clsw,
           const void* __restrict__ clsb, float* __restrict__ outf,
           unsigned short* __restrict__ outu, const int* __restrict__ flags) {
    __shared__ float pooled[256];
    int g = blockIdx.x, c = threadIdx.x;
    int f = flags[0];
    int cnt = pcnt[g];
    for (int m = c; m < 256; m += 64) {
        float mean = psum[g * 256 + m] / (float)(cnt > 0 ? cnt : 1);
        float mx = (cnt > 0) ? fdec(pkey[g * 256 + m]) : 0.f;
        pooled[m] = mean + mx;
    }
    __syncthreads();
    float a = ldf(clsb, c, f);
    for (int m = 0; m < 256; ++m) a += pooled[m] * ldf(clsw, (size_t)m * 64 + c, f);
    if (f) outf[g * 64 + c] = a;
    else   outu[g * 64 + c] = f2bf(a);
}

extern "C" void kernel_launch(void* const* d_in, const int* in_sizes, int n_in,
                              void* d_out, int out_size, void* d_ws, size_t ws_size,
                              hipStream_t stream) {
    const void*           X     = d_in[0];
    const int*            EI    = (const int*)d_in[1];
    const int*            BATCH = (const int*)d_in[3];
    const void*           PREW  = d_in[4];
    const void*           PREB  = d_in[5];
    const void*           GCNW  = d_in[6];
    const void*           GCNB  = d_in[7];
    const void*           CLSW  = d_in[8];
    const void*           CLSB  = d_in[9];

    const int N = in_sizes[3];
    const int E = in_sizes[1] / 2;

    char* ws = (char*)d_ws;
    size_t off = 0;
    auto alloc = [&](size_t b) { size_t o = off; off += (b + 255) & ~(size_t)255; return o; };
    int*            flags  = (int*)(ws + alloc(256));
    float*          dinv   = (float*)(ws + alloc((size_t)N * 4));
    int*            hist   = (int*)(ws + alloc((size_t)N * 4));
    int*            cursor = (int*)(ws + alloc((size_t)N * 4));
    int*            rowptr = (int*)(ws + alloc((size_t)(N + 1) * 4));
    int*            col    = (int*)(ws + alloc((size_t)E * 4));
    unsigned short* Wt0    = (unsigned short*)(ws + alloc(256 * 256 * 2));
    unsigned short* Wt1    = (unsigned short*)(ws + alloc(256 * 512 * 2));
    float*          cvec   = (float*)(ws + alloc(512 * 4));
    float*          dvec   = (float*)(ws + alloc(512 * 4));
    float*          psum   = (float*)(ws + alloc(64 * 256 * 4));
    unsigned int*   pkey   = (unsigned int*)(ws + alloc(64 * 256 * 4));
    int*            pcnt   = (int*)(ws + alloc(64 * 4));
    unsigned short* U      = (unsigned short*)(ws + alloc((size_t)N * 256 * 2));
    unsigned short* Y      = (unsigned short*)(ws + alloc((size_t)N * 256 * 2));

    (void)hipMemsetAsync(hist, 0, (size_t)N * 4, stream);
    (void)hipMemsetAsync(cursor, 0, (size_t)N * 4, stream);
    (void)hipMemsetAsync(psum, 0, 64 * 256 * 4, stream);
    (void)hipMemsetAsync(pkey, 0, 64 * 256 * 4, stream);
    (void)hipMemsetAsync(pcnt, 0, 64 * 4, stream);

    int xstride = (in_sizes[0] / 2) / 1024; if (xstride < 1) xstride = 1;
    int estride = E / 1024;                 if (estride < 1) estride = 1;
    k_detect<<<1, 256, 0, stream>>>((const unsigned short*)X, xstride, EI, estride, flags);

    k_hist<<<(E + 255) / 256, 256, 0, stream>>>(EI, E, N, hist, flags);
    k_dinv<<<(N + 255) / 256, 256, 0, stream>>>(hist, dinv, N);
    k_scan<<<1, 1024, 0, stream>>>(hist, rowptr, N);
    k_scatter<<<(E + 255) / 256, 256, 0, stream>>>(EI, E, N, rowptr, cursor, col, flags);
    k_prepw<<<dim3(256, 3), 256, 0, stream>>>(PREW, GCNW, Wt0, Wt1, flags);
    k_prepb<<<2, 256, 0, stream>>>(PREB, GCNW, GCNB, cvec, dvec, flags);

    dim3 ggrid((N + 127) / 128, 2);
    k_gemm<<<ggrid, 256, 0, stream>>>(X, U, Wt0, cvec, dinv, U, N, 256, flags);
    k_agg<<<(N + 3) / 4, 256, 0, stream>>>(U, rowptr, col, dinv, dvec, Y, N);
    k_gemm<<<ggrid, 256, 0, stream>>>(X, Y, Wt1, cvec + 256, dinv, U, N, 512, flags);
    k_agg<<<(N + 3) / 4, 256, 0, stream>>>(U, rowptr, col, dinv, dvec + 256, Y, N);
    k_pool<<<(N + 63) / 64, 256, 0, stream>>>(Y, BATCH, N, psum, pkey, pcnt, flags);
    k_cls<<<64, 64, 0, stream>>>(psum, pkey, pcnt, CLSW, CLSB,
                                 (float*)d_out, (unsigned short*)d_out, flags);
}

// Round 3
// 592.793 us; speedup vs baseline: 1.0922x; 1.0922x over previous
//
#include <hip/hip_runtime.h>

typedef __attribute__((ext_vector_type(8))) short bf16x8;
typedef __attribute__((ext_vector_type(4))) float f32x4;

__device__ inline float bf2f(unsigned short u) {
    union { float f; unsigned int i; } v; v.i = ((unsigned int)u) << 16; return v.f;
}
__device__ inline unsigned short f2bf(float f) {
    union { float f; unsigned int u; } v; v.f = f;
    unsigned int x = v.u;
    unsigned int r = x + 0x7FFFu + ((x >> 16) & 1u);
    return (unsigned short)(r >> 16);
}
// order-preserving float <-> uint for atomicMax
__device__ inline unsigned int fenc(float x) {
    union { float f; unsigned int u; } v; v.f = x;
    return (v.u & 0x80000000u) ? ~v.u : (v.u | 0x80000000u);
}
__device__ inline float fdec(unsigned int k) {
    union { float f; unsigned int u; } v;
    v.u = (k & 0x80000000u) ? (k & 0x7FFFFFFFu) : ~k;
    return v.f;
}
// dual-format loads: f32flag ? float32 buffer : bf16 buffer
__device__ inline float ldf(const void* p, size_t i, int f32) {
    return f32 ? ((const float*)p)[i] : bf2f(((const unsigned short*)p)[i]);
}
// i64flag ? int64 buffer (values < 2^31, take low word) : int32 buffer
__device__ inline int ldi(const int* p, size_t i, int i64) {
    return i64 ? p[2 * i] : p[i];
}

// ---------------- format detection (device-side, deterministic) ----------------
__global__ __launch_bounds__(256)
void k_detect(const unsigned short* __restrict__ xu, int xstride,
              const int* __restrict__ ei, int estride, int* __restrict__ flags) {
    __shared__ int cnt, orv;
    if (threadIdx.x == 0) { cnt = 0; orv = 0; }
    __syncthreads();
    int c = 0, o = 0;
    for (int s = 0; s < 4; ++s) {
        int j = threadIdx.x * 4 + s;               // 0..1023
        size_t k = (size_t)j * xstride;            // < xelems/2
        unsigned short u = xu[2 * k];              // even ushort
        int e = (u >> 7) & 0xFF;
        if (e >= 100 && e <= 140) ++c;             // sane bf16 exponent?
        size_t idx = (size_t)j * estride;          // < E
        o |= ei[2 * idx + 1];                      // odd word
    }
    atomicAdd(&cnt, c); atomicOr(&orv, o);
    __syncthreads();
    if (threadIdx.x == 0) {
        flags[0] = (cnt < 768) ? 1 : 0;   // 1 => floats are f32
        flags[1] = (orv == 0) ? 1 : 0;    // 1 => ints are int64
    }
}

// ---------------- zero scratch (replaces 5 memsets) ----------------
__global__ void k_zero(int* __restrict__ hist, int* __restrict__ cursor,
                       float* __restrict__ psum, unsigned int* __restrict__ pkey,
                       int* __restrict__ pcnt, int N) {
    int t = blockIdx.x * 256 + threadIdx.x;
    if (t < N) hist[t] = 0;
    else if (t < 2 * N) cursor[t - N] = 0;
    else if (t < 2 * N + 16384) psum[t - 2 * N] = 0.f;
    else if (t < 2 * N + 32768) pkey[t - 2 * N - 16384] = 0u;
    else if (t < 2 * N + 32768 + 64) pcnt[t - 2 * N - 32768] = 0;
}

// ---------------- X -> bf16 conversion (or copy if already bf16) ----------------
__global__ __launch_bounds__(256)
void k_cvt(const void* __restrict__ X, unsigned short* __restrict__ Xb,
           size_t nelem, const int* __restrict__ flags) {
    int f = flags[0];
    size_t i = ((size_t)blockIdx.x * 256 + threadIdx.x) * 8;
    if (i >= nelem) return;
    if (f) {
        const float* s = (const float*)X + i;
        float4 f0 = *(const float4*)s;
        float4 f1 = *(const float4*)(s + 4);
        int4 o;
        o.x = (int)f2bf(f0.x) | ((int)f2bf(f0.y) << 16);
        o.y = (int)f2bf(f0.z) | ((int)f2bf(f0.w) << 16);
        o.z = (int)f2bf(f1.x) | ((int)f2bf(f1.y) << 16);
        o.w = (int)f2bf(f1.z) | ((int)f2bf(f1.w) << 16);
        *(int4*)(Xb + i) = o;
    } else {
        *(int4*)(Xb + i) = *(const int4*)((const unsigned short*)X + i);
    }
}

// ---------------- CSR build ----------------
__global__ void k_hist(const int* __restrict__ ei, int E, int N,
                       int* __restrict__ hist, const int* __restrict__ flags) {
    int e = blockIdx.x * 256 + threadIdx.x;
    if (e >= E) return;
    int i64 = flags[1];
    int d = ldi(ei, (size_t)E + e, i64); d = d < 0 ? 0 : (d >= N ? N - 1 : d);
    atomicAdd(&hist[d], 1);
}

__global__ void k_dinv(const int* __restrict__ hist, float* __restrict__ dinv, int N) {
    int i = blockIdx.x * 256 + threadIdx.x;
    if (i < N) dinv[i] = rsqrtf((float)(hist[i] + 1));
}

__global__ __launch_bounds__(1024)
void k_scan(const int* __restrict__ hist, int* __restrict__ rowptr, int N) {
    __shared__ int ssum[1024];
    int t = threadIdx.x;
    int chunk = (N + 1023) / 1024;
    int lo = t * chunk, hi = lo + chunk; if (hi > N) hi = N; if (lo > N) lo = N;
    int s = 0;
#pragma unroll 4
    for (int i = lo; i < hi; ++i) s += hist[i];
    ssum[t] = s;
    __syncthreads();
    for (int off = 1; off < 1024; off <<= 1) {
        int v = (t >= off) ? ssum[t - off] : 0;
        __syncthreads();
        ssum[t] += v;
        __syncthreads();
    }
    int run = ssum[t] - s;
    for (int i = lo; i < hi; ++i) { rowptr[i] = run; run += hist[i]; }
    if (t == 1023) rowptr[N] = ssum[1023];
}

__global__ void k_scatter(const int* __restrict__ ei, int E, int N,
                          const int* __restrict__ rowptr, int* __restrict__ cursor,
                          int* __restrict__ col, const int* __restrict__ flags) {
    int e = blockIdx.x * 256 + threadIdx.x;
    if (e >= E) return;
    int i64 = flags[1];
    int s = ldi(ei, (size_t)e, i64);     s = s < 0 ? 0 : (s >= N ? N - 1 : s);
    int d = ldi(ei, (size_t)E + e, i64); d = d < 0 ? 0 : (d >= N ? N - 1 : d);
    int pos = rowptr[d] + atomicAdd(&cursor[d], 1);
    col[pos] = s;
}

// ---------------- weight folding (fp32 math, bf16 store) ----------------
// which=0: Wt0[n*256+k]     = 2*(pw(0,0)@gw(0,0))[k][n] + (pw(0,1)@gw(0,1))[k][n]
// which=1: Wt1[n*512+k]     = 2*(pw(1,0)@gw(1,0))[k][n]
// which=2: Wt1[n*512+256+k] =   (pw(1,1)@gw(1,1))[k][n]
// grid (16, 3), 256 thr: block computes 16 k-rows for all n; pre_w tile in LDS.
__global__ __launch_bounds__(256)
void k_prepw(const void* __restrict__ pre_w, const void* __restrict__ gcn_w,
             unsigned short* __restrict__ Wt0, unsigned short* __restrict__ Wt1,
             const int* __restrict__ flags) {
    __shared__ float pa[16][256];
    __shared__ float pb[16][256];
    const int which = blockIdx.y;
    const int k0 = blockIdx.x * 16;
    const int n = threadIdx.x;
    const int f = flags[0];
    size_t baseA, baseB = 0, baseG;
    if (which == 0)      { baseA = (size_t)(0   + k0) * 256; baseB = (size_t)(256 + k0) * 256; baseG = 0; }
    else if (which == 1) { baseA = (size_t)(512 + k0) * 256; baseG = 2 * 65536; }
    else                 { baseA = (size_t)(768 + k0) * 256; baseG = 3 * 65536; }
    for (int t = threadIdx.x; t < 16 * 256; t += 256) {
        int kk = t >> 8, m = t & 255;
        pa[kk][m] = ldf(pre_w, baseA + (size_t)kk * 256 + m, f);
        if (which == 0) pb[kk][m] = ldf(pre_w, baseB + (size_t)kk * 256 + m, f);
    }
    __syncthreads();
    float a[16] = {};
    if (which == 0) {
        float b[16] = {};
#pragma unroll 2
        for (int m = 0; m < 256; ++m) {
            float gv0 = ldf(gcn_w, baseG + (size_t)m * 256 + n, f);
            float gv1 = ldf(gcn_w, 65536 + (size_t)m * 256 + n, f);
#pragma unroll
            for (int kk = 0; kk < 16; ++kk) {
                a[kk] += pa[kk][m] * gv0;
                b[kk] += pb[kk][m] * gv1;
            }
        }
#pragma unroll
        for (int kk = 0; kk < 16; ++kk)
            Wt0[(size_t)n * 256 + k0 + kk] = f2bf(2.f * a[kk] + b[kk]);
    } else {
#pragma unroll 2
        for (int m = 0; m < 256; ++m) {
            float gv = ldf(gcn_w, baseG + (size_t)m * 256 + n, f);
#pragma unroll
            for (int kk = 0; kk < 16; ++kk) a[kk] += pa[kk][m] * gv;
        }
        if (which == 1) {
#pragma unroll
            for (int kk = 0; kk < 16; ++kk)
                Wt1[(size_t)n * 512 + k0 + kk] = f2bf(2.f * a[kk]);
        } else {
#pragma unroll
            for (int kk = 0; kk < 16; ++kk)
                Wt1[(size_t)n * 512 + 256 + k0 + kk] = f2bf(a[kk]);
        }
    }
}

__global__ void k_prepb(const void* __restrict__ pre_b, const void* __restrict__ gcn_w,
                        const void* __restrict__ gcn_b,
                        float* __restrict__ cvec, float* __restrict__ dvec,
                        const int* __restrict__ flags) {
    int l = blockIdx.x, n = threadIdx.x;
    int f = flags[0];
    size_t pb0 = (size_t)(l * 2 + 0) * 256;
    size_t pb1 = (size_t)(l * 2 + 1) * 256;
    size_t g0 = (size_t)(l * 2 + 0) * 256 * 256;
    size_t g1 = (size_t)(l * 2 + 1) * 256 * 256;
    float a = 0.f, b = 0.f;
#pragma unroll 4
    for (int m = 0; m < 256; ++m) {
        a += ldf(pre_b, pb0 + m, f) * ldf(gcn_w, g0 + (size_t)m * 256 + n, f);
        b += ldf(pre_b, pb1 + m, f) * ldf(gcn_w, g1 + (size_t)m * 256 + n, f);
    }
    cvec[l * 256 + n] = 2.f * a + b;
    dvec[l * 256 + n] = 2.f * ldf(gcn_b, (size_t)(l * 2 + 0) * 256 + n, f)
                            + ldf(gcn_b, (size_t)(l * 2 + 1) * 256 + n, f);
}

// ---------------- main GEMM: out[i,:] = dinv[i] * (A[i,:] @ W + c) ----------------
// A row: k<256 from Xb (bf16), k>=256 from Yb (bf16). Wt is [256 x K] bf16 (W^T).
// 128x128 tile, BK=64, 4 waves (2x2), XOR-swizzled LDS.
__global__ __launch_bounds__(256)
void k_gemm(const unsigned short* __restrict__ Xb, const unsigned short* __restrict__ Yb,
            const unsigned short* __restrict__ Wt, const float* __restrict__ cvec,
            const float* __restrict__ dinv, unsigned short* __restrict__ out,
            int M, int K) {
    __shared__ unsigned short lds[2 * 128 * 64];  // A tile + W tile, 16KB each
    char* ldsb = (char*)lds;
    const int tid = threadIdx.x;
    const int lane = tid & 63;
    const int wid = tid >> 6;
    const int wm = wid >> 1, wn = wid & 1;
    const int row0 = blockIdx.x * 128;
    const int bn = blockIdx.y;

    f32x4 acc[4][4] = {};
    const int KT = K / 64;
    for (int kt = 0; kt < KT; ++kt) {
        const int k0 = kt * 64;
        const unsigned short* Asrc = (k0 < 256) ? Xb : Yb;
        const int ak0 = (k0 < 256) ? k0 : k0 - 256;
        int4 ra[4], rw[4];
#pragma unroll
        for (int q = 0; q < 4; ++q) {
            int id = q * 256 + tid;        // 0..1023 chunks of 16B (8 bf16)
            int r = id >> 3;               // tile row 0..127
            int cb = id & 7;               // chunk in row
            int grow = row0 + r; if (grow > M - 1) grow = M - 1;
            ra[q] = *(const int4*)(Asrc + (size_t)grow * 256 + ak0 + cb * 8);
            rw[q] = *(const int4*)(Wt + (size_t)(bn * 128 + r) * K + k0 + cb * 8);
        }
        __syncthreads();   // prior LDS reads done
#pragma unroll
        for (int q = 0; q < 4; ++q) {
            int id = q * 256 + tid;
            int r = id >> 3, cb = id & 7;
            int sw = (cb * 16) ^ ((r & 7) << 4);
            *(int4*)(ldsb + r * 128 + sw) = ra[q];
            *(int4*)(ldsb + 16384 + r * 128 + sw) = rw[q];
        }
        __syncthreads();
#pragma unroll
        for (int kk = 0; kk < 2; ++kk) {
            bf16x8 af[4], bfr[4];
            int byte = kk * 64 + ((lane >> 4) << 4);
#pragma unroll
            for (int m = 0; m < 4; ++m) {
                int r = wm * 64 + m * 16 + (lane & 15);
                af[m] = *(const bf16x8*)(ldsb + r * 128 + (byte ^ ((r & 7) << 4)));
            }
#pragma unroll
            for (int n = 0; n < 4; ++n) {
                int r = wn * 64 + n * 16 + (lane & 15);
                bfr[n] = *(const bf16x8*)(ldsb + 16384 + r * 128 + (byte ^ ((r & 7) << 4)));
            }
#pragma unroll
            for (int m = 0; m < 4; ++m)
#pragma unroll
                for (int n = 0; n < 4; ++n)
                    acc[m][n] = __builtin_amdgcn_mfma_f32_16x16x32_bf16(af[m], bfr[n], acc[m][n], 0, 0, 0);
        }
    }
    // epilogue: val = (acc + c[col]) * dinv[row], bf16 store
#pragma unroll
    for (int m = 0; m < 4; ++m) {
#pragma unroll
        for (int j = 0; j < 4; ++j) {
            int rt = wm * 64 + m * 16 + ((lane >> 4) << 2) + j;
            int grow = row0 + rt;
            if (grow < M) {
                float di = dinv[grow];
#pragma unroll
                for (int n = 0; n < 4; ++n) {
                    int colc = bn * 128 + wn * 64 + n * 16 + (lane & 15);
                    float v = (acc[m][n][j] + cvec[colc]) * di;
                    out[(size_t)grow * 256 + colc] = f2bf(v);
                }
            }
        }
    }
}

// ---------------- aggregation: Y[i] = dinv[i]*(U[i] + sum_{j in in(i)} U[j]) + d ----------------
// wave = one node; 8-deep unrolled gather for memory-level parallelism.
__global__ __launch_bounds__(256)
void k_agg(const unsigned short* __restrict__ U, const int* __restrict__ rowptr,
           const int* __restrict__ col, const float* __restrict__ dinv,
           const float* __restrict__ dvec, unsigned short* __restrict__ Y, int N) {
    int w = (blockIdx.x * 256 + threadIdx.x) >> 6;   // node per wave
    int lane = threadIdx.x & 63;
    if (w >= N) return;
    const size_t loff = (size_t)lane * 4;
    ushort4 sv = *(const ushort4*)(U + (size_t)w * 256 + loff);
    float a0 = bf2f(sv.x), a1 = bf2f(sv.y), a2 = bf2f(sv.z), a3 = bf2f(sv.w);
    int beg = rowptr[w], end = rowptr[w + 1];
    int e = beg;
    for (; e + 8 <= end; e += 8) {
        int s0 = __builtin_amdgcn_readfirstlane(col[e + 0]);
        int s1 = __builtin_amdgcn_readfirstlane(col[e + 1]);
        int s2 = __builtin_amdgcn_readfirstlane(col[e + 2]);
        int s3 = __builtin_amdgcn_readfirstlane(col[e + 3]);
        int s4 = __builtin_amdgcn_readfirstlane(col[e + 4]);
        int s5 = __builtin_amdgcn_readfirstlane(col[e + 5]);
        int s6 = __builtin_amdgcn_readfirstlane(col[e + 6]);
        int s7 = __builtin_amdgcn_readfirstlane(col[e + 7]);
        ushort4 v0 = *(const ushort4*)(U + (size_t)s0 * 256 + loff);
        ushort4 v1 = *(const ushort4*)(U + (size_t)s1 * 256 + loff);
        ushort4 v2 = *(const ushort4*)(U + (size_t)s2 * 256 + loff);
        ushort4 v3 = *(const ushort4*)(U + (size_t)s3 * 256 + loff);
        ushort4 v4 = *(const ushort4*)(U + (size_t)s4 * 256 + loff);
        ushort4 v5 = *(const ushort4*)(U + (size_t)s5 * 256 + loff);
        ushort4 v6 = *(const ushort4*)(U + (size_t)s6 * 256 + loff);
        ushort4 v7 = *(const ushort4*)(U + (size_t)s7 * 256 + loff);
        a0 += (bf2f(v0.x) + bf2f(v1.x)) + (bf2f(v2.x) + bf2f(v3.x))
            + (bf2f(v4.x) + bf2f(v5.x)) + (bf2f(v6.x) + bf2f(v7.x));
        a1 += (bf2f(v0.y) + bf2f(v1.y)) + (bf2f(v2.y) + bf2f(v3.y))
            + (bf2f(v4.y) + bf2f(v5.y)) + (bf2f(v6.y) + bf2f(v7.y));
        a2 += (bf2f(v0.z) + bf2f(v1.z)) + (bf2f(v2.z) + bf2f(v3.z))
            + (bf2f(v4.z) + bf2f(v5.z)) + (bf2f(v6.z) + bf2f(v7.z));
        a3 += (bf2f(v0.w) + bf2f(v1.w)) + (bf2f(v2.w) + bf2f(v3.w))
            + (bf2f(v4.w) + bf2f(v5.w)) + (bf2f(v6.w) + bf2f(v7.w));
    }
    for (; e < end; ++e) {
        int s = __builtin_amdgcn_readfirstlane(col[e]);
        ushort4 v = *(const ushort4*)(U + (size_t)s * 256 + loff);
        a0 += bf2f(v.x); a1 += bf2f(v.y); a2 += bf2f(v.z); a3 += bf2f(v.w);
    }
    float di = dinv[w];
    int f = lane * 4;
    a0 = a0 * di + dvec[f + 0];
    a1 = a1 * di + dvec[f + 1];
    a2 = a2 * di + dvec[f + 2];
    a3 = a3 * di + dvec[f + 3];
    ushort4 o; o.x = f2bf(a0); o.y = f2bf(a1); o.z = f2bf(a2); o.w = f2bf(a3);
    *(ushort4*)(Y + (size_t)w * 256 + loff) = o;
}

// ---------------- pooling (batch is sorted) ----------------
__global__ __launch_bounds__(256)
void k_pool(const unsigned short* __restrict__ Y, const int* __restrict__ batch, int N,
            float* __restrict__ psum, unsigned int* __restrict__ pkey, int* __restrict__ pcnt,
            const int* __restrict__ flags) {
    int f = threadIdx.x;
    int base = blockIdx.x * 64;
    if (base >= N) return;
    int i64 = flags[1];
    int g0 = ldi(batch, base, i64); int curg = g0 < 0 ? 0 : (g0 > 63 ? 63 : g0);
    float s = 0.f, mx = -__builtin_inff(); int cnt = 0;
#pragma unroll 4
    for (int r = 0; r < 64; ++r) {
        int node = base + r;
        if (node >= N) break;
        int g = ldi(batch, node, i64); g = g < 0 ? 0 : (g > 63 ? 63 : g);
        if (g != curg) {
            atomicAdd(&psum[curg * 256 + f], s);
            atomicMax(&pkey[curg * 256 + f], fenc(mx));
            if (f == 0) atomicAdd(&pcnt[curg], cnt);
            curg = g; s = 0.f; mx = -__builtin_inff(); cnt = 0;
        }
        float v = bf2f(Y[(size_t)node * 256 + f]);
        s += v; mx = fmaxf(mx, v); ++cnt;
    }
    atomicAdd(&psum[curg * 256 + f], s);
    atomicMax(&pkey[curg * 256 + f], fenc(mx));
    if (f == 0) atomicAdd(&pcnt[curg], cnt);
}

// ---------------- classifier ----------------
__global__ __launch_bounds__(64)
void k_cls(const float* __restrict__ psum, const unsigned int* __restrict__ pkey,
           const int* __restrict__ pcnt, const void* __restrict__ clsw,
           const void* __restrict__ clsb, float* __restrict__ outf,
           unsigned short* __restrict__ outu, const int* __restrict__ flags) {
    __shared__ float pooled[256];
    int g = blockIdx.x, c = threadIdx.x;
    int f = flags[0];
    int cnt = pcnt[g];
    for (int m = c; m < 256; m += 64) {
        float mean = psum[g * 256 + m] / (float)(cnt > 0 ? cnt : 1);
        float mx = (cnt > 0) ? fdec(pkey[g * 256 + m]) : 0.f;
        pooled[m] = mean + mx;
    }
    __syncthreads();
    float a = ldf(clsb, c, f);
#pragma unroll 8
    for (int m = 0; m < 256; ++m) a += pooled[m] * ldf(clsw, (size_t)m * 64 + c, f);
    if (f) outf[g * 64 + c] = a;
    else   outu[g * 64 + c] = f2bf(a);
}

extern "C" void kernel_launch(void* const* d_in, const int* in_sizes, int n_in,
                              void* d_out, int out_size, void* d_ws, size_t ws_size,
                              hipStream_t stream) {
    const void*           X     = d_in[0];
    const int*            EI    = (const int*)d_in[1];
    const int*            BATCH = (const int*)d_in[3];
    const void*           PREW  = d_in[4];
    const void*           PREB  = d_in[5];
    const void*           GCNW  = d_in[6];
    const void*           GCNB  = d_in[7];
    const void*           CLSW  = d_in[8];
    const void*           CLSB  = d_in[9];

    const int N = in_sizes[3];
    const int E = in_sizes[1] / 2;

    char* ws = (char*)d_ws;
    size_t off = 0;
    auto alloc = [&](size_t b) { size_t o = off; off += (b + 255) & ~(size_t)255; return o; };
    int*            flags  = (int*)(ws + alloc(256));
    float*          dinv   = (float*)(ws + alloc((size_t)N * 4));
    int*            hist   = (int*)(ws + alloc((size_t)N * 4));
    int*            cursor = (int*)(ws + alloc((size_t)N * 4));
    int*            rowptr = (int*)(ws + alloc((size_t)(N + 1) * 4));
    int*            col    = (int*)(ws + alloc((size_t)E * 4));
    unsigned short* Wt0    = (unsigned short*)(ws + alloc(256 * 256 * 2));
    unsigned short* Wt1    = (unsigned short*)(ws + alloc(256 * 512 * 2));
    float*          cvec   = (float*)(ws + alloc(512 * 4));
    float*          dvec   = (float*)(ws + alloc(512 * 4));
    float*          psum   = (float*)(ws + alloc(64 * 256 * 4));
    unsigned int*   pkey   = (unsigned int*)(ws + alloc(64 * 256 * 4));
    int*            pcnt   = (int*)(ws + alloc(64 * 4));
    unsigned short* Xb     = (unsigned short*)(ws + alloc((size_t)N * 256 * 2));
    unsigned short* U      = (unsigned short*)(ws + alloc((size_t)N * 256 * 2));
    unsigned short* Y      = (unsigned short*)(ws + alloc((size_t)N * 256 * 2));

    int zt = 2 * N + 32768 + 64;
    k_zero<<<(zt + 255) / 256, 256, 0, stream>>>(hist, cursor, psum, pkey, pcnt, N);

    int xstride = (in_sizes[0] / 2) / 1024; if (xstride < 1) xstride = 1;
    int estride = E / 1024;                 if (estride < 1) estride = 1;
    k_detect<<<1, 256, 0, stream>>>((const unsigned short*)X, xstride, EI, estride, flags);

    size_t xelem = (size_t)N * 256;
    k_cvt<<<(int)((xelem / 8 + 255) / 256), 256, 0, stream>>>(X, Xb, xelem, flags);

    k_hist<<<(E + 255) / 256, 256, 0, stream>>>(EI, E, N, hist, flags);
    k_dinv<<<(N + 255) / 256, 256, 0, stream>>>(hist, dinv, N);
    k_scan<<<1, 1024, 0, stream>>>(hist, rowptr, N);
    k_scatter<<<(E + 255) / 256, 256, 0, stream>>>(EI, E, N, rowptr, cursor, col, flags);
    k_prepw<<<dim3(16, 3), 256, 0, stream>>>(PREW, GCNW, Wt0, Wt1, flags);
    k_prepb<<<2, 256, 0, stream>>>(PREB, GCNW, GCNB, cvec, dvec, flags);

    dim3 ggrid((N + 127) / 128, 2);
    k_gemm<<<ggrid, 256, 0, stream>>>(Xb, U, Wt0, cvec, dinv, U, N, 256);
    k_agg<<<(N + 3) / 4, 256, 0, stream>>>(U, rowptr, col, dinv, dvec, Y, N);
    k_gemm<<<ggrid, 256, 0, stream>>>(Xb, Y, Wt1, cvec + 256, dinv, U, N, 512);
    k_agg<<<(N + 3) / 4, 256, 0, stream>>>(U, rowptr, col, dinv, dvec + 256, Y, N);
    k_pool<<<(N + 63) / 64, 256, 0, stream>>>(Y, BATCH, N, psum, pkey, pcnt, flags);
    k_cls<<<64, 64, 0, stream>>>(psum, pkey, pcnt, CLSW, CLSB,
                                 (float*)d_out, (unsigned short*)d_out, flags);
}